// Round 5
// baseline (104.503 us; speedup 1.0000x reference)
//
#include <hip/hip_runtime.h>
#include <hip/hip_bf16.h>

#define N_IN   256
#define N_HID  128
#define N_ELEM 5
#define ROWB   1040            // 1024 B row + 16 B pad
#define BUF    (16 * ROWB)     // 16640 B per tile buffer
#define NBLK   768             // persistent 1-wave blocks (3 per CU)
#define CHUNK_MAX 20           // max subtiles per wave (ceil(12504/768)=17)

typedef __attribute__((ext_vector_type(8))) short  short8;
typedef __attribute__((ext_vector_type(4))) short  short4v;
typedef __attribute__((ext_vector_type(4))) float  float4v;

__device__ __forceinline__ int expert_of(int z) {
    return (z == 1) ? 0 : (z == 6) ? 1 : (z == 7) ? 2 : (z == 8) ? 3 : 4;
}

__device__ __forceinline__ short f2bf(float f) {
    union { float f; unsigned u; } c; c.f = f;
    unsigned r = (c.u + 0x7fffu + ((c.u >> 16) & 1u)) >> 16;
    return (short)r;
}

#define GLOAD_LDS16(gsrc, ldst) \
    __builtin_amdgcn_global_load_lds((const __attribute__((address_space(1))) void*)(gsrc), \
                                     (__attribute__((address_space(3))) void*)(ldst), 16, 0, 0)

#define WAITV(n) asm volatile("s_waitcnt vmcnt(" #n ")" ::: "memory")

// ---------------- fused: W1 fp32->bf16 convert + element histogram -------------
__global__ void prep_hist_kernel(const float* __restrict__ W1, short* __restrict__ W1b,
                                 int nbW, const int* __restrict__ z, int n,
                                 int* __restrict__ counts) {
    if ((int)blockIdx.x < nbW) {
        int i = (blockIdx.x * 256 + threadIdx.x) * 4;
        float4v f = *(const float4v*)(W1 + i);
        short4v s;
        s[0] = f2bf(f[0]); s[1] = f2bf(f[1]); s[2] = f2bf(f[2]); s[3] = f2bf(f[3]);
        *(short4v*)(W1b + i) = s;
        return;
    }
    __shared__ int cnt[N_ELEM];
    if (threadIdx.x < N_ELEM) cnt[threadIdx.x] = 0;
    __syncthreads();
    int i = (blockIdx.x - nbW) * blockDim.x + threadIdx.x;
    if (i < n) atomicAdd(&cnt[expert_of(z[i])], 1);
    __syncthreads();
    if (threadIdx.x < N_ELEM && cnt[threadIdx.x]) atomicAdd(&counts[threadIdx.x], cnt[threadIdx.x]);
}

// ---------------- meta: per-expert atom offset/count + 16-row tile prefix ------
__global__ void build_meta_kernel(const int* __restrict__ counts, int* __restrict__ cursor,
                                  int* __restrict__ meta) {
    if (threadIdx.x == 0) {
        int o = 0, tp = 0;
        for (int e = 0; e < N_ELEM; ++e) {
            int c = counts[e];
            meta[e] = o; meta[5 + e] = c; meta[10 + e] = tp;
            cursor[e] = o;
            o += c; tp += (c + 15) >> 4;
        }
        meta[15] = tp;
    }
}

// ---------------- scatter atoms into expert-sorted perm ------------------------
__global__ void scatter_kernel(const int* __restrict__ z, int n,
                               int* __restrict__ cursor, int* __restrict__ perm) {
    __shared__ int cnt[N_ELEM], cur[N_ELEM], base[N_ELEM];
    int tid = threadIdx.x;
    if (tid < N_ELEM) { cnt[tid] = 0; cur[tid] = 0; }
    __syncthreads();
    int i = blockIdx.x * blockDim.x + tid;
    int e = -1;
    if (i < n) { e = expert_of(z[i]); atomicAdd(&cnt[e], 1); }
    __syncthreads();
    if (tid < N_ELEM) base[tid] = cnt[tid] ? atomicAdd(&cursor[tid], cnt[tid]) : 0;
    __syncthreads();
    if (e >= 0) {
        int r = atomicAdd(&cur[e], 1);
        perm[base[e] + r] = i;
    }
}

// ---------------- persistent 1-wave blocks, 3-deep counted-vmcnt pipeline ------
// Steady-state vmcnt ops per iteration: exactly 16 DMAs + 1 store. gids come
// from LDS (lgkm domain). Waits: prologue {32,33}, steady 34, tail {18,2}.
__launch_bounds__(64, 1)
__global__ void mlp_kernel(const float* __restrict__ X, const short* __restrict__ W1b,
                           const float* __restrict__ B1f, const float* __restrict__ W2f,
                           const float* __restrict__ B2f, const int* __restrict__ perm,
                           const int* __restrict__ meta, float* __restrict__ out) {
    __shared__ char Abuf[3 * BUF];          // 49920 B
    __shared__ int  gidT[CHUNK_MAX * 16];   // 1280 B

    int lane = threadIdx.x;
    int am = lane & 15, g = lane >> 4;

    int so0 = meta[0], so1 = meta[1], so2 = meta[2], so3 = meta[3], so4 = meta[4];
    int ct0 = meta[5], ct1 = meta[6], ct2 = meta[7], ct3 = meta[8], ct4 = meta[9];
    int tp0 = meta[10], tp1 = meta[11], tp2 = meta[12], tp3 = meta[13], tp4 = meta[14];
    int tp5 = meta[15];

    int nSub = tp5;
    int chunk = (nSub + NBLK - 1) / NBLK;
    int s0 = blockIdx.x * chunk, s1 = min(s0 + chunk, nSub);
    if (s0 >= s1) return;
    int L = s1 - s0;

    // ---- stage this wave's gid table into LDS (4 tiles per iteration)
    for (int st = 0; st < L; st += 4) {
        int sl = s0 + st + g;               // g = lane>>4 picks the tile
        if (sl < s1) {
            int e = (sl >= tp1) + (sl >= tp2) + (sl >= tp3) + (sl >= tp4);
            int so = so0, ct = ct0, t0 = tp0;
            if (e == 1) { so = so1; ct = ct1; t0 = tp1; }
            else if (e == 2) { so = so2; ct = ct2; t0 = tp2; }
            else if (e == 3) { so = so3; ct = ct3; t0 = tp3; }
            else if (e == 4) { so = so4; ct = ct4; t0 = tp4; }
            int rs = so + (sl - t0) * 16;
            int last = so + ct - 1;
            gidT[(st + g) * 16 + am] = perm[min(rs + am, last)];
        }
    }

#define LOADGV(s_, gv_) gv_ = gidT[((s_) - s0) * 16 + am]

#define ISSUE(s_, buf_, gv_) do {                                             \
    _Pragma("unroll")                                                         \
    for (int j_ = 0; j_ < 16; ++j_) {                                         \
        int gu_ = __shfl((gv_), j_, 64);                                      \
        GLOAD_LDS16(X + (size_t)gu_ * N_IN + lane * 4, (buf_) + j_ * ROWB);   \
    } } while (0)

#define COMPUTE(cb_, gvv_, s_) do {                                           \
    int rs_ = segA0 + ((s_) - segT0) * 16;                                    \
    int rows_ = min(16, segAE - rs_);                                         \
    const char* arow_ = (cb_) + am * ROWB + g * 32;                           \
    float4v acc_[8] = {};                                                     \
    _Pragma("unroll")                                                         \
    for (int kk = 0; kk < 8; ++kk) {                                          \
        float4v f0_ = *(const float4v*)(arow_ + kk * 128);                    \
        float4v f1_ = *(const float4v*)(arow_ + kk * 128 + 16);               \
        short8 aa_;                                                           \
        aa_[0]=f2bf(f0_[0]); aa_[1]=f2bf(f0_[1]);                             \
        aa_[2]=f2bf(f0_[2]); aa_[3]=f2bf(f0_[3]);                             \
        aa_[4]=f2bf(f1_[0]); aa_[5]=f2bf(f1_[1]);                             \
        aa_[6]=f2bf(f1_[2]); aa_[7]=f2bf(f1_[3]);                             \
        _Pragma("unroll")                                                     \
        for (int n_ = 0; n_ < 8; ++n_)                                        \
            acc_[n_] = __builtin_amdgcn_mfma_f32_16x16x32_bf16(aa_, bfrag[n_][kk], acc_[n_], 0, 0, 0); \
    }                                                                         \
    float p0_=0, p1_=0, p2_=0, p3_=0;                                         \
    _Pragma("unroll")                                                         \
    for (int n_ = 0; n_ < 8; ++n_) {                                          \
        float v0_=acc_[n_][0]+b1c[n_]; v0_=v0_/(1.0f+__expf(-v0_));           \
        float v1_=acc_[n_][1]+b1c[n_]; v1_=v1_/(1.0f+__expf(-v1_));           \
        float v2_=acc_[n_][2]+b1c[n_]; v2_=v2_/(1.0f+__expf(-v2_));           \
        float v3_=acc_[n_][3]+b1c[n_]; v3_=v3_/(1.0f+__expf(-v3_));           \
        p0_+=v0_*w2c[n_]; p1_+=v1_*w2c[n_]; p2_+=v2_*w2c[n_]; p3_+=v3_*w2c[n_]; \
    }                                                                         \
    _Pragma("unroll")                                                         \
    for (int sh_ = 1; sh_ <= 8; sh_ <<= 1) {                                  \
        p0_+=__shfl_xor(p0_,sh_,64); p1_+=__shfl_xor(p1_,sh_,64);             \
        p2_+=__shfl_xor(p2_,sh_,64); p3_+=__shfl_xor(p3_,sh_,64);             \
    }                                                                         \
    int rr_ = am & 3;                                                         \
    float val_ = (rr_==0)?p0_:(rr_==1)?p1_:(rr_==2)?p2_:p3_;                  \
    int tgt_ = __shfl((gvv_), g * 4 + rr_, 64);                               \
    if (am < 4 && (g * 4 + rr_) < rows_) out[tgt_] = val_ + b2v;              \
} while (0)

    char* Bu0 = Abuf;
    char* Bu1 = Abuf + BUF;
    char* Bu2 = Abuf + 2 * BUF;

    for (int e = 0; e < N_ELEM; ++e) {
        int tpe  = (e==0)?tp0:(e==1)?tp1:(e==2)?tp2:(e==3)?tp3:tp4;
        int tpe1 = (e==0)?tp1:(e==1)?tp2:(e==2)?tp3:(e==3)?tp4:tp5;
        int a = max(s0, tpe), b = min(s1, tpe1);
        if (a >= b) continue;
        int segA0 = (e==0)?so0:(e==1)?so1:(e==2)?so2:(e==3)?so3:so4;
        int segCt = (e==0)?ct0:(e==1)?ct1:(e==2)?ct2:(e==3)?ct3:ct4;
        int segT0 = tpe, segAE = segA0 + segCt;

        // expert weights -> registers (drained below; outside the counted loop)
        const short* Wb = W1b + e * (N_HID * N_IN);
        short8 bfrag[8][8];
        float b1c[8], w2c[8];
#pragma unroll
        for (int n = 0; n < 8; ++n) {
#pragma unroll
            for (int kk = 0; kk < 8; ++kk)
                bfrag[n][kk] = *(const short8*)(Wb + (n * 16 + am) * N_IN + kk * 32 + g * 8);
            int c = n * 16 + am;
            b1c[n] = B1f[e * N_HID + c];
            w2c[n] = W2f[e * N_HID + c];
        }
        float b2v = B2f[e];
        WAITV(0);                       // clean vmcnt baseline for the segment

        int Lseg = b - a;
        if (Lseg >= 4) {
            int g0, g1, g2;
            LOADGV(a + 0, g0); ISSUE(a + 0, Bu0, g0);
            LOADGV(a + 1, g1); ISSUE(a + 1, Bu1, g1);
            LOADGV(a + 2, g2); ISSUE(a + 2, Bu2, g2);
            WAITV(32); COMPUTE(Bu0, g0, a + 0);
            // k = 1 (always valid for Lseg >= 4)
            LOADGV(a + 3, g0); ISSUE(a + 3, Bu0, g0);
            WAITV(33); COMPUTE(Bu1, g1, a + 1);
            int k = 2;
            int kend = Lseg - 3;        // last k that issues
            for (; k + 2 <= kend; k += 3) {
                LOADGV(a + k + 2, g1); ISSUE(a + k + 2, Bu1, g1);
                WAITV(34); COMPUTE(Bu2, g2, a + k);
                LOADGV(a + k + 3, g2); ISSUE(a + k + 3, Bu2, g2);
                WAITV(34); COMPUTE(Bu0, g0, a + k + 1);
                LOADGV(a + k + 4, g0); ISSUE(a + k + 4, Bu0, g0);
                WAITV(34); COMPUTE(Bu1, g1, a + k + 2);
            }
            if (k <= kend) {            // k % 3 == 2
                LOADGV(a + k + 2, g1); ISSUE(a + k + 2, Bu1, g1);
                WAITV(34); COMPUTE(Bu2, g2, a + k);
                ++k;
            }
            if (k <= kend) {            // k % 3 == 0
                LOADGV(a + k + 2, g2); ISSUE(a + k + 2, Bu2, g2);
                WAITV(34); COMPUTE(Bu0, g0, a + k);
                ++k;
            }
            // tail: k == Lseg-2; two tiles left at runtime ring positions
            {
                int m = k - (k / 3) * 3;
                char* cbA = (m == 0) ? Bu0 : (m == 1) ? Bu1 : Bu2;
                int  gvA  = (m == 0) ? g0  : (m == 1) ? g1  : g2;
                WAITV(18); COMPUTE(cbA, gvA, a + k);
                int m2 = (m + 1 == 3) ? 0 : m + 1;
                char* cbB = (m2 == 0) ? Bu0 : (m2 == 1) ? Bu1 : Bu2;
                int  gvB  = (m2 == 0) ? g0  : (m2 == 1) ? g1  : g2;
                WAITV(2); COMPUTE(cbB, gvB, a + k + 1);
            }
        } else {
            for (int s = a; s < b; ++s) {
                int gv; LOADGV(s, gv); ISSUE(s, Bu0, gv);
                WAITV(0); COMPUTE(Bu0, gv, s);
            }
        }
    }
#undef LOADGV
#undef ISSUE
#undef COMPUTE
}

// ---------------- launch -------------------------------------------------------
extern "C" void kernel_launch(void* const* d_in, const int* in_sizes, int n_in,
                              void* d_out, int out_size, void* d_ws, size_t ws_size,
                              hipStream_t stream) {
    const int*   z  = (const int*)  d_in[0];
    const float* X  = (const float*)d_in[1];
    const float* W1 = (const float*)d_in[2];
    const float* B1 = (const float*)d_in[3];
    const float* W2 = (const float*)d_in[4];
    const float* B2 = (const float*)d_in[5];
    float* out = (float*)d_out;
    int nAtoms = in_sizes[0];

    char* ws = (char*)d_ws;
    size_t off = 0;
    short* W1b  = (short*)(ws + off); off += (size_t)N_ELEM * N_HID * N_IN * 2;
    int* perm   = (int*)(ws + off); off += (size_t)nAtoms * 4;
    int* counts = (int*)(ws + off); off += 32;
    int* cursor = (int*)(ws + off); off += 32;
    int* meta   = (int*)(ws + off); off += 64;

    hipMemsetAsync(counts, 0, 32, stream);

    int wElems = N_ELEM * N_HID * N_IN;        // 163840 = 160 * 256 * 4
    int nbW = wElems / (256 * 4);
    int hb  = (nAtoms + 255) / 256;
    prep_hist_kernel<<<nbW + hb, 256, 0, stream>>>(W1, W1b, nbW, z, nAtoms, counts);
    build_meta_kernel<<<1, 64, 0, stream>>>(counts, cursor, meta);
    scatter_kernel<<<hb, 256, 0, stream>>>(z, nAtoms, cursor, perm);
    mlp_kernel<<<NBLK, 64, 0, stream>>>(X, W1b, B1, W2, B2, perm, meta, out);
}

// Round 6
// 95.137 us; speedup vs baseline: 1.0984x; 1.0984x over previous
//
#include <hip/hip_runtime.h>
#include <hip/hip_bf16.h>

#define N_IN    256
#define N_HID   128
#define N_ELEM  5
#define ROWB    1040               // LDS bytes per staged row (1024 + 16 pad)
#define BUFB    (64 * ROWB)        // 66560 B per tile buffer
#define NBLK    512
#define CHUNK_MAX 8

typedef __attribute__((ext_vector_type(8))) short  short8;
typedef __attribute__((ext_vector_type(4))) short  short4v;
typedef __attribute__((ext_vector_type(4))) float  float4v;
typedef __attribute__((ext_vector_type(4))) int    int4v;

__device__ __forceinline__ int expert_of(int z) {
    return (z == 1) ? 0 : (z == 6) ? 1 : (z == 7) ? 2 : (z == 8) ? 3 : 4;
}
__device__ __forceinline__ short f2bf(float f) {
    union { float f; unsigned u; } c; c.f = f;
    unsigned r = (c.u + 0x7fffu + ((c.u >> 16) & 1u)) >> 16;
    return (short)r;
}

#define AS3 __attribute__((address_space(3)))
#define GLOAD_LDS16(gsrc, ldst) \
    __builtin_amdgcn_global_load_lds((const __attribute__((address_space(1))) void*)(gsrc), \
                                     (AS3 void*)(ldst), 16, 0, 0)
__device__ __forceinline__ unsigned lds_off(const void* p) {
    return (unsigned)(size_t)(AS3 const char*)p;
}

// ---- inline-asm LDS ops: invisible to the waitcnt legalizer (no auto vmcnt(0))
#define DSR128(dst, a) asm volatile("ds_read_b128 %0, %1" : "=v"(dst) : "v"(a))
#define DSR32(dst, a)  asm volatile("ds_read_b32 %0, %1"  : "=v"(dst) : "v"(a))
#define DSW32(a, val)  asm volatile("ds_write_b32 %0, %1" :: "v"(a), "v"(val) : "memory")
#define SWIZ(dst, src, MASKSTR) \
    asm volatile("ds_swizzle_b32 %0, %1 offset:" MASKSTR : "=v"(dst) : "v"(src))
#define LGKM0 do { asm volatile("s_waitcnt lgkmcnt(0)" ::: "memory"); \
                   __builtin_amdgcn_sched_barrier(0); } while (0)
#define LGKM8 do { asm volatile("s_waitcnt lgkmcnt(8)" ::: "memory"); \
                   __builtin_amdgcn_sched_barrier(0); } while (0)
#define WAITV(n) do { asm volatile("s_waitcnt vmcnt(" #n ")" ::: "memory"); \
                      __builtin_amdgcn_sched_barrier(0); } while (0)
#define BAR() do { __builtin_amdgcn_s_barrier(); \
                   __builtin_amdgcn_sched_barrier(0); } while (0)

// ---------------- prep: W1 fp32->bf16 + histogram -----------------------------
__global__ void prep_hist_kernel(const float* __restrict__ W1, short* __restrict__ W1b,
                                 int nbW, const int* __restrict__ z, int n,
                                 int* __restrict__ counts) {
    if ((int)blockIdx.x < nbW) {
        int i = (blockIdx.x * 256 + threadIdx.x) * 4;
        float4v f = *(const float4v*)(W1 + i);
        short4v s;
        s[0] = f2bf(f[0]); s[1] = f2bf(f[1]); s[2] = f2bf(f[2]); s[3] = f2bf(f[3]);
        *(short4v*)(W1b + i) = s;
        return;
    }
    __shared__ int cnt[N_ELEM];
    if (threadIdx.x < N_ELEM) cnt[threadIdx.x] = 0;
    __syncthreads();
    int i = (blockIdx.x - nbW) * blockDim.x + threadIdx.x;
    if (i < n) atomicAdd(&cnt[expert_of(z[i])], 1);
    __syncthreads();
    if (threadIdx.x < N_ELEM && cnt[threadIdx.x]) atomicAdd(&counts[threadIdx.x], cnt[threadIdx.x]);
}

// ---------------- meta: per-expert offset/count + 64-row tile prefix ----------
__global__ void build_meta_kernel(const int* __restrict__ counts, int* __restrict__ cursor,
                                  int* __restrict__ meta) {
    if (threadIdx.x == 0) {
        int o = 0, tp = 0;
        for (int e = 0; e < N_ELEM; ++e) {
            int c = counts[e];
            meta[e] = o; meta[5 + e] = c; meta[10 + e] = tp;
            cursor[e] = o;
            o += c; tp += (c + 63) >> 6;
        }
        meta[15] = tp;
    }
}

// ---------------- scatter atoms into expert-sorted perm ------------------------
__global__ void scatter_kernel(const int* __restrict__ z, int n,
                               int* __restrict__ cursor, int* __restrict__ perm) {
    __shared__ int cnt[N_ELEM], cur[N_ELEM], base[N_ELEM];
    int tid = threadIdx.x;
    if (tid < N_ELEM) { cnt[tid] = 0; cur[tid] = 0; }
    __syncthreads();
    int i = blockIdx.x * blockDim.x + tid;
    int e = -1;
    if (i < n) { e = expert_of(z[i]); atomicAdd(&cnt[e], 1); }
    __syncthreads();
    if (tid < N_ELEM) base[tid] = cnt[tid] ? atomicAdd(&cursor[tid], cnt[tid]) : 0;
    __syncthreads();
    if (e >= 0) {
        int r = atomicAdd(&cur[e], 1);
        perm[base[e] + r] = i;
    }
}

// ---------------- mlp: 4 waves share a 64-atom tile, depth-2 DMA pipeline -----
// Steady FIFO per wave/iter = 16 DMA + 1 store. WAITV(16): with <=33 outstanding
// it retires L(t)+S(t-1) exactly; first iter 32 outstanding -> retires L(t0).
// All in-loop LDS traffic is inline asm -> no compiler-inserted vmcnt(0) drains.
__launch_bounds__(256, 1)
__global__ void mlp_kernel(const float* __restrict__ X, const short* __restrict__ W1b,
                           const float* __restrict__ B1f, const float* __restrict__ W2f,
                           const float* __restrict__ B2f, const int* __restrict__ perm,
                           const int* __restrict__ meta, float* __restrict__ out) {
    __shared__ char  Xs[2 * BUFB];            // 133120 B
    __shared__ int   gidT[CHUNK_MAX * 64];    // 2048 B
    __shared__ float part[64 * 4];            // 1024 B

    int tid  = threadIdx.x;
    int lane = tid & 63;
    int w    = tid >> 6;
    int am   = lane & 15, g = lane >> 4;

    int so0 = meta[0], so1 = meta[1], so2 = meta[2], so3 = meta[3], so4 = meta[4];
    int ct0 = meta[5], ct1 = meta[6], ct2 = meta[7], ct3 = meta[8], ct4 = meta[9];
    int tp1 = meta[11], tp2 = meta[12], tp3 = meta[13], tp4 = meta[14];
    int nSub = meta[15];

    int q = nSub / NBLK, r = nSub % NBLK;
    int b = blockIdx.x;
    int t0 = b * q + min(b, r);
    int t1 = t0 + q + (b < r ? 1 : 0);
    if (t0 >= t1) return;
    int Lc = t1 - t0;

    // ---- stage gid table (pre-pipeline; normal ops OK here)
    for (int i = tid; i < Lc * 64; i += 256) {
        int tl = t0 + (i >> 6);
        int e = (tl >= tp1) + (tl >= tp2) + (tl >= tp3) + (tl >= tp4);
        int so = so0, ct = ct0, tb = 0;
        if (e == 1) { so = so1; ct = ct1; tb = tp1; }
        else if (e == 2) { so = so2; ct = ct2; tb = tp2; }
        else if (e == 3) { so = so3; ct = ct3; tb = tp3; }
        else if (e == 4) { so = so4; ct = ct4; tb = tp4; }
        int rs = so + (tl - tb) * 64;
        gidT[i] = perm[min(rs + (i & 63), so + ct - 1)];
    }
    __syncthreads();     // full drain once, before any DMA — clean FIFO baseline

    unsigned XS_OFF = lds_off(Xs);
    unsigned GID_OFF = lds_off(gidT);
    unsigned P_OFF = lds_off(part);

#define PREFETCH(tl_, bsel_) do {                                               \
    unsigned gb_ = GID_OFF + (unsigned)((((tl_) - t0) * 64 + w * 16) * 4);      \
    unsigned gr_[16];                                                           \
    _Pragma("unroll")                                                           \
    for (int j_ = 0; j_ < 16; ++j_) DSR32(gr_[j_], gb_ + j_ * 4);               \
    LGKM0;                                                                      \
    _Pragma("unroll")                                                           \
    for (int j_ = 0; j_ < 16; ++j_) {                                           \
        const float* src_ = X + ((size_t)gr_[j_] << 8) + (lane << 2);           \
        GLOAD_LDS16(src_, Xs + (bsel_) * BUFB + (w * 16 + j_) * ROWB);          \
    } } while (0)

    int ecur = -1;
    short8 bfrag[2][8];
    float b1c[2], w2c[2], b2v = 0.0f;

    PREFETCH(t0, 0);

    for (int t = t0; t < t1; ++t) {
        int lt = t - t0;
        int bsel = lt & 1;
        if (t + 1 < t1) { PREFETCH(t + 1, bsel ^ 1); WAITV(16); }
        else           { WAITV(0); }
        BAR();                                   // tile t fully staged (all waves)

        int e = (t >= tp1) + (t >= tp2) + (t >= tp3) + (t >= tp4);
        if (e != ecur) {                         // rare (<=4 boundary tiles total)
            ecur = e;
            const short* Wb = W1b + e * (N_HID * N_IN);
#pragma unroll
            for (int ni = 0; ni < 2; ++ni) {
                int c = w * 32 + ni * 16 + am;
#pragma unroll
                for (int kk = 0; kk < 8; ++kk)
                    bfrag[ni][kk] = *(const short8*)(Wb + c * N_IN + kk * 32 + g * 8);
                b1c[ni] = B1f[e * N_HID + c];
                w2c[ni] = W2f[e * N_HID + c];
            }
            b2v = B2f[e];
        }

        // ---- K loop: asm ds_read_b128 double-buffered by kk, counted lgkm
        unsigned ab0 = XS_OFF + bsel * BUFB + (0 * 16 + am) * ROWB + g * 32;
        unsigned ab1 = ab0 + 16 * ROWB;
        unsigned ab2 = ab0 + 32 * ROWB;
        unsigned ab3 = ab0 + 48 * ROWB;
        float4v acc[4][2] = {};
        float4v rd[2][4][2];
        DSR128(rd[0][0][0], ab0); DSR128(rd[0][0][1], ab0 + 16);
        DSR128(rd[0][1][0], ab1); DSR128(rd[0][1][1], ab1 + 16);
        DSR128(rd[0][2][0], ab2); DSR128(rd[0][2][1], ab2 + 16);
        DSR128(rd[0][3][0], ab3); DSR128(rd[0][3][1], ab3 + 16);
#pragma unroll
        for (int kk = 0; kk < 8; ++kk) {
            if (kk < 7) {
                unsigned o = (kk + 1) * 128;
                DSR128(rd[(kk + 1) & 1][0][0], ab0 + o); DSR128(rd[(kk + 1) & 1][0][1], ab0 + o + 16);
                DSR128(rd[(kk + 1) & 1][1][0], ab1 + o); DSR128(rd[(kk + 1) & 1][1][1], ab1 + o + 16);
                DSR128(rd[(kk + 1) & 1][2][0], ab2 + o); DSR128(rd[(kk + 1) & 1][2][1], ab2 + o + 16);
                DSR128(rd[(kk + 1) & 1][3][0], ab3 + o); DSR128(rd[(kk + 1) & 1][3][1], ab3 + o + 16);
                LGKM8;
            } else {
                LGKM0;
            }
#pragma unroll
            for (int mi = 0; mi < 4; ++mi) {
                float4v f0 = rd[kk & 1][mi][0], f1 = rd[kk & 1][mi][1];
                union { __hip_bfloat162 h[4]; short8 s; } a;
                a.h[0] = __float22bfloat162_rn({f0[0], f0[1]});
                a.h[1] = __float22bfloat162_rn({f0[2], f0[3]});
                a.h[2] = __float22bfloat162_rn({f1[0], f1[1]});
                a.h[3] = __float22bfloat162_rn({f1[2], f1[3]});
                acc[mi][0] = __builtin_amdgcn_mfma_f32_16x16x32_bf16(a.s, bfrag[0][kk], acc[mi][0], 0, 0, 0);
                acc[mi][1] = __builtin_amdgcn_mfma_f32_16x16x32_bf16(a.s, bfrag[1][kk], acc[mi][1], 0, 0, 0);
            }
        }

        // ---- bias + silu + per-lane dot over this wave's 32 hidden
        float pv[4][4];
#pragma unroll
        for (int mi = 0; mi < 4; ++mi)
#pragma unroll
            for (int rr = 0; rr < 4; ++rr) {
                float s = 0.0f;
#pragma unroll
                for (int ni = 0; ni < 2; ++ni) {
                    float v = acc[mi][ni][rr] + b1c[ni];
                    v = v / (1.0f + __expf(-v));
                    s += v * w2c[ni];
                }
                pv[mi][rr] = s;
            }

        // ---- butterfly reduce over the 16 am-lanes (asm ds_swizzle)
        {
            float tv[4][4];
#define RSTAGE(MASK)                                                            \
            _Pragma("unroll")                                                   \
            for (int mi = 0; mi < 4; ++mi) {                                    \
                SWIZ(tv[mi][0], pv[mi][0], MASK); SWIZ(tv[mi][1], pv[mi][1], MASK); \
                SWIZ(tv[mi][2], pv[mi][2], MASK); SWIZ(tv[mi][3], pv[mi][3], MASK); \
            }                                                                   \
            LGKM0;                                                              \
            _Pragma("unroll")                                                   \
            for (int mi = 0; mi < 4; ++mi) {                                    \
                pv[mi][0] += tv[mi][0]; pv[mi][1] += tv[mi][1];                 \
                pv[mi][2] += tv[mi][2]; pv[mi][3] += tv[mi][3];                 \
            }
            RSTAGE("0x041F") RSTAGE("0x081F") RSTAGE("0x101F") RSTAGE("0x201F")
#undef RSTAGE
        }

        // ---- cross-wave partial exchange (asm LDS) + store
        if (am < 4) {
#pragma unroll
            for (int mi = 0; mi < 4; ++mi) {
                float val = (am == 0) ? pv[mi][0] : (am == 1) ? pv[mi][1]
                           : (am == 2) ? pv[mi][2] : pv[mi][3];
                unsigned pa = P_OFF + (unsigned)(((mi * 16 + g * 4 + am) * 4 + w) * 4);
                DSW32(pa, val);
            }
        }
        LGKM0;
        BAR();
        {
            float4v s4;
            unsigned ra = P_OFF + (unsigned)((w * 16 + am) * 16);
            DSR128(s4, ra);
            unsigned gidf;
            unsigned ga = GID_OFF + (unsigned)((lt * 64 + w * 16 + am) * 4);
            DSR32(gidf, ga);
            LGKM0;
            float y = s4[0] + s4[1] + s4[2] + s4[3] + b2v;
            out[gidf] = y;          // all 64 lanes; g-replicas write same value
        }
        BAR();
    }
#undef PREFETCH
}

// ---------------- launch -------------------------------------------------------
extern "C" void kernel_launch(void* const* d_in, const int* in_sizes, int n_in,
                              void* d_out, int out_size, void* d_ws, size_t ws_size,
                              hipStream_t stream) {
    const int*   z  = (const int*)  d_in[0];
    const float* X  = (const float*)d_in[1];
    const float* W1 = (const float*)d_in[2];
    const float* B1 = (const float*)d_in[3];
    const float* W2 = (const float*)d_in[4];
    const float* B2 = (const float*)d_in[5];
    float* out = (float*)d_out;
    int nAtoms = in_sizes[0];

    char* ws = (char*)d_ws;
    size_t off = 0;
    short* W1b  = (short*)(ws + off); off += (size_t)N_ELEM * N_HID * N_IN * 2;
    int* perm   = (int*)(ws + off); off += (size_t)nAtoms * 4;
    int* counts = (int*)(ws + off); off += 32;
    int* cursor = (int*)(ws + off); off += 32;
    int* meta   = (int*)(ws + off); off += 64;

    hipMemsetAsync(counts, 0, 32, stream);

    int wElems = N_ELEM * N_HID * N_IN;        // 163840 = 160 * 256 * 4
    int nbW = wElems / (256 * 4);
    int hb  = (nAtoms + 255) / 256;
    prep_hist_kernel<<<nbW + hb, 256, 0, stream>>>(W1, W1b, nbW, z, nAtoms, counts);
    build_meta_kernel<<<1, 64, 0, stream>>>(counts, cursor, meta);
    scatter_kernel<<<hb, 256, 0, stream>>>(z, nAtoms, cursor, perm);
    mlp_kernel<<<NBLK, 256, 0, stream>>>(X, W1b, B1, W2, B2, perm, meta, out);
}